// Round 9
// baseline (1833.673 us; speedup 1.0000x reference)
//
#include <hip/hip_runtime.h>
#include <cstdint>
#include <climits>
#include <math.h>

#define NN 50000
#define EE 1600000
#define GG 512
#define NEG_SLOPE 0.2f
#define NB 196          // ceil(NN/256) scan blocks
#define EAW 12          // padded dwords per packed-fp16 ea row (48 B, 16B-aligned)

typedef _Float16 half2v __attribute__((ext_vector_type(2)));

__device__ __forceinline__ uint32_t packh2(float a, float b) {
    union { half2v h; uint32_t u; } c;
    c.h = half2v{(_Float16)a, (_Float16)b};
    return c.u;
}
__device__ __forceinline__ float2 h2f(uint32_t u) {
    union { uint32_t u; half2v h; } c;
    c.u = u;
    return make_float2((float)c.h[0], (float)c.h[1]);
}
__device__ __forceinline__ float fdot2u(uint32_t a, uint32_t b, float c) {
    union { uint32_t u; half2v h; } ua, ub;
    ua.u = a; ub.u = b;
    return __builtin_amdgcn_fdot2(ua.h, ub.h, c, false);
}

// ---------- pack ea rows to fp16 half2 dwords (9 used + 3 pad) ----------
__global__ void k_pack_ea(const float* __restrict__ ea, uint32_t* __restrict__ eah) {
    int t = blockIdx.x * blockDim.x + threadIdx.x;
    if (t >= EE * EAW) return;
    int e = t / EAW, kk = t - e * EAW;
    uint32_t v = 0;
    if (kk < 9) {
        float2 q = *(const float2*)(ea + (size_t)e * 18 + 2 * kk);
        v = packh2(q.x, q.y);
    }
    eah[t] = v;
}

// ---------- degree histogram ----------
__global__ void k_hist(const int* __restrict__ dst, int* __restrict__ hist) {
    int e = blockIdx.x * blockDim.x + threadIdx.x;
    if (e < EE) atomicAdd(&hist[dst[e]], 1);
}

// ---------- CSR build: scan of hist then scatter (real edges only) ----------
__global__ void k_scan_a(const int* __restrict__ hist, int* __restrict__ bsum) {
    __shared__ int tmp[256];
    int i = blockIdx.x * 256 + threadIdx.x;
    tmp[threadIdx.x] = (i < NN) ? hist[i] : 0;
    __syncthreads();
    for (int d = 128; d; d >>= 1) {
        if (threadIdx.x < d) tmp[threadIdx.x] += tmp[threadIdx.x + d];
        __syncthreads();
    }
    if (threadIdx.x == 0) bsum[blockIdx.x] = tmp[0];
}

__global__ void k_scan_b(int* __restrict__ bsum, int* __restrict__ rowptr) {
    int acc = 0;
    for (int b = 0; b < NB; b++) { int v = bsum[b]; bsum[b] = acc; acc += v; }
    rowptr[NN] = acc;  // == EE
}

__global__ void k_scan_c(const int* __restrict__ hist, const int* __restrict__ bsum,
                         int* __restrict__ rowptr) {
    __shared__ int tmp[256];
    int i = blockIdx.x * 256 + threadIdx.x;
    int v = (i < NN) ? hist[i] : 0;
    tmp[threadIdx.x] = v;
    __syncthreads();
    for (int d = 1; d < 256; d <<= 1) {
        int t = (threadIdx.x >= d) ? tmp[threadIdx.x - d] : 0;
        __syncthreads();
        tmp[threadIdx.x] += t;
        __syncthreads();
    }
    if (i < NN) rowptr[i] = tmp[threadIdx.x] - v + bsum[blockIdx.x];
}

__global__ void k_cursor_init(const int* __restrict__ rowptr, int* __restrict__ cursor) {
    int i = blockIdx.x * blockDim.x + threadIdx.x;
    if (i < NN) cursor[i] = rowptr[i];
}

__global__ void k_scatter(const int* __restrict__ dst, int* __restrict__ cursor,
                          int* __restrict__ csr_eid) {
    int e = blockIdx.x * blockDim.x + threadIdx.x;
    if (e < EE) {
        int p = atomicAdd(&cursor[dst[e]], 1);
        csr_eid[p] = e;
    }
}

// ---------- combine Wl|Wr into padded Wc [K x NP], biases into bc [NP] ----------
__global__ void k_combine_w(const float* __restrict__ Wl, const float* __restrict__ bl,
                            const float* __restrict__ Wr, const float* __restrict__ br,
                            float* __restrict__ Wc, float* __restrict__ bc,
                            int K, int C, int NP) {
    int t = blockIdx.x * blockDim.x + threadIdx.x;
    if (t < K * NP) {
        int k = t / NP, n = t - k * NP;
        float v = 0.0f;
        if (n < C) v = Wl[k * C + n];
        else if (n < 2 * C) v = Wr[k * C + n - C];
        Wc[t] = v;
    }
    if (t < NP) {
        float v = 0.0f;
        if (t < C) v = bl[t];
        else if (t < 2 * C) v = br[t - C];
        bc[t] = v;
    }
}

// ---------- tiled dual GEMM: A[NN x K] @ Wc[K x NP]; cols<C -> xlh (fp16 packed),
// cols C..2C-1 -> xr (fp32). BM=64, BN=64, BK=16, 256 threads, 4x4 micro-tile. ----------
template <int KK, int NP, int C>
__global__ void __launch_bounds__(256)
k_gemm_dual(const float* __restrict__ A, const float* __restrict__ Wc,
            const float* __restrict__ bc, uint32_t* __restrict__ xlh, float* __restrict__ xr) {
    constexpr int BM = 64, BN = 64, BK = 16;
    __shared__ float As[BK][BM];   // transposed A tile
    __shared__ float Ws[BK][BN];
    const int tidx = threadIdx.x;
    const int tx = tidx & 15;      // N dir
    const int ty = tidx >> 4;      // M dir
    const int m0 = blockIdx.x * BM;
    const int n0 = blockIdx.y * BN;

    float acc[4][4];
#pragma unroll
    for (int i2 = 0; i2 < 4; i2++)
#pragma unroll
        for (int j2 = 0; j2 < 4; j2++) acc[i2][j2] = 0.0f;

    for (int k0 = 0; k0 < KK; k0 += BK) {
        {
            int m = tidx >> 2;
            int kq = (tidx & 3) * 4;
            float4 v = make_float4(0.f, 0.f, 0.f, 0.f);
            if (m0 + m < NN && k0 + kq < KK)
                v = *(const float4*)(A + (size_t)(m0 + m) * KK + k0 + kq);
            As[kq + 0][m] = v.x; As[kq + 1][m] = v.y;
            As[kq + 2][m] = v.z; As[kq + 3][m] = v.w;
        }
        {
            int k = tidx >> 4;
            int nq = (tidx & 15) * 4;
            float4 v = make_float4(0.f, 0.f, 0.f, 0.f);
            if (k0 + k < KK)
                v = *(const float4*)(Wc + (size_t)(k0 + k) * NP + n0 + nq);
            *(float4*)&Ws[k][nq] = v;
        }
        __syncthreads();
#pragma unroll
        for (int k = 0; k < BK; k++) {
            float a[4], b[4];
            *(float4*)a = *(const float4*)&As[k][ty * 4];
            *(float4*)b = *(const float4*)&Ws[k][tx * 4];
#pragma unroll
            for (int i2 = 0; i2 < 4; i2++)
#pragma unroll
                for (int j2 = 0; j2 < 4; j2++) acc[i2][j2] += a[i2] * b[j2];
        }
        __syncthreads();
    }

    const int n = n0 + tx * 4;
    float4 bcv = *(const float4*)(bc + n);
#pragma unroll
    for (int i2 = 0; i2 < 4; i2++) {
        int m = m0 + ty * 4 + i2;
        if (m >= NN) continue;
        float o0 = acc[i2][0] + bcv.x, o1 = acc[i2][1] + bcv.y;
        float o2 = acc[i2][2] + bcv.z, o3 = acc[i2][3] + bcv.w;
        if (n < C) {
            uint32_t* p = xlh + (size_t)m * (C / 2) + (n >> 1);
            p[0] = packh2(o0, o1);
            p[1] = packh2(o2, o3);
        } else if (n < 2 * C) {
            *(float4*)(xr + (size_t)m * C + n - C) = make_float4(o0, o1, o2, o3);
        }
    }
}

// ---------- fused per-dst-node: scores + online softmax + aggregate ----------
// Wave per node; lane l (< C/VEC) owns channels [l*VEC, l*VEC+VEC).
// xl gathered as packed fp16 (xlh); unroll-2 double-buffered prefetch; branchless.
template <int C, int VEC, int RELU>
__global__ void __launch_bounds__(256, 4)
k_fused_node(const int* __restrict__ rowptr, const int* __restrict__ csr_eid,
             const int* __restrict__ srcv, const uint32_t* __restrict__ eah,
             const float* __restrict__ We, const float* __restrict__ att,
             const uint32_t* __restrict__ xlh, const float* __restrict__ xr,
             const float* __restrict__ bias, float* __restrict__ out) {
    constexpr int NL = C / VEC;
    constexpr int HW = VEC / 2;          // packed dwords per lane
    constexpr int ROWD = C / 2;          // dwords per xlh row
    const int lane = threadIdx.x & 63;
    int wid = blockIdx.x * (blockDim.x >> 6) + (threadIdx.x >> 6);
    int nw = gridDim.x * (blockDim.x >> 6);
    const bool act = lane < NL;
    const int laneC = (act ? lane : 0);  // clamp so idle lanes load safely

    uint32_t Wfp[9][VEC];
    float af[VEC], bv[VEC];
    if (act) {
#pragma unroll
        for (int kk = 0; kk < 9; kk++)
#pragma unroll
            for (int j = 0; j < VEC; j++) {
                int col = lane * VEC + j;
                Wfp[kk][j] = packh2(We[(2 * kk) * C + col], We[(2 * kk + 1) * C + col]);
            }
#pragma unroll
        for (int j = 0; j < VEC; j++) { af[j] = att[lane * VEC + j]; bv[j] = bias[lane * VEC + j]; }
    } else {
#pragma unroll
        for (int kk = 0; kk < 9; kk++)
#pragma unroll
            for (int j = 0; j < VEC; j++) Wfp[kk][j] = 0;
#pragma unroll
        for (int j = 0; j < VEC; j++) { af[j] = 0.f; bv[j] = 0.f; }
    }

    for (int i = wid; i < NN; i += nw) {
        int beg = __builtin_amdgcn_readfirstlane(rowptr[i]);
        int end = __builtin_amdgcn_readfirstlane(rowptr[i + 1]);

        // own rows: xl (fp16->fp32) and xr (fp32)
        float xlv[VEC], xrv[VEC];
        {
            const uint32_t* lp = xlh + (size_t)i * ROWD + laneC * HW;
#pragma unroll
            for (int h = 0; h < HW; h++) {
                float2 f = h2f(lp[h]);
                xlv[2 * h] = f.x; xlv[2 * h + 1] = f.y;
            }
            const float* rp = xr + (size_t)i * C + laneC * VEC;
#pragma unroll
            for (int j = 0; j < VEC; j++) xrv[j] = rp[j];
            if (!act) {
#pragma unroll
                for (int j = 0; j < VEC; j++) { xlv[j] = 0.f; xrv[j] = 0.f; }
            }
        }

        float m = -INFINITY, zs = 0.0f;
        float acc[VEC], wsum[VEC];
#pragma unroll
        for (int j = 0; j < VEC; j++) { acc[j] = 0.f; wsum[j] = 0.f; }

        for (int cs = beg; cs < end; cs += 64) {
            int cnt = end - cs; if (cnt > 64) cnt = 64;
            int eid_l = 0, src_l = 0;
            if (lane < cnt) {
                eid_l = csr_eid[cs + lane];
                src_l = srcv[eid_l];
            }

            // double buffers
            uint32_t eab[2][9];
            uint32_t xvb[2][HW];
            {
                int e0 = __builtin_amdgcn_readlane(eid_l, 0);
                int s0 = __builtin_amdgcn_readlane(src_l, 0);
                const uint32_t* ep = eah + (size_t)e0 * EAW;
                uint4 q0 = *(const uint4*)ep;
                uint4 q1 = *(const uint4*)(ep + 4);
                eab[0][0] = q0.x; eab[0][1] = q0.y; eab[0][2] = q0.z; eab[0][3] = q0.w;
                eab[0][4] = q1.x; eab[0][5] = q1.y; eab[0][6] = q1.z; eab[0][7] = q1.w;
                eab[0][8] = ep[8];
                const uint32_t* xp = xlh + (size_t)s0 * ROWD + laneC * HW;
#pragma unroll
                for (int h = 0; h < HW; h++) xvb[0][h] = xp[h];
            }

#pragma unroll 2
            for (int t = 0; t < cnt; t++) {
                const int cur = t & 1, nxt = cur ^ 1;
                // branchless prefetch of t+1 (clamped)
                {
                    int tp = t + 1 < cnt ? t + 1 : cnt - 1;
                    int e1 = __builtin_amdgcn_readlane(eid_l, tp);
                    int s1 = __builtin_amdgcn_readlane(src_l, tp);
                    const uint32_t* ep = eah + (size_t)e1 * EAW;
                    uint4 q0 = *(const uint4*)ep;
                    uint4 q1 = *(const uint4*)(ep + 4);
                    eab[nxt][0] = q0.x; eab[nxt][1] = q0.y; eab[nxt][2] = q0.z; eab[nxt][3] = q0.w;
                    eab[nxt][4] = q1.x; eab[nxt][5] = q1.y; eab[nxt][6] = q1.z; eab[nxt][7] = q1.w;
                    eab[nxt][8] = ep[8];
                    const uint32_t* xp = xlh + (size_t)s1 * ROWD + laneC * HW;
#pragma unroll
                    for (int h = 0; h < HW; h++) xvb[nxt][h] = xp[h];
                }

                // unpack xv once (used by score and accumulate)
                float xv[VEC];
#pragma unroll
                for (int h = 0; h < HW; h++) {
                    float2 f = h2f(xvb[cur][h]);
                    xv[2 * h] = f.x; xv[2 * h + 1] = f.y;
                }

                float part = 0.0f;
#pragma unroll
                for (int j = 0; j < VEC; j++) {
                    float w = 0.0f;
#pragma unroll
                    for (int kk = 0; kk < 9; kk++) w = fdot2u(eab[cur][kk], Wfp[kk][j], w);
                    wsum[j] += w;
                    float u = xv[j] + xrv[j] + w;
                    float h = fmaxf(u, 0.0f) + NEG_SLOPE * fminf(u, 0.0f);
                    part += af[j] * h;
                }
#pragma unroll
                for (int off = 32; off; off >>= 1) part += __shfl_xor(part, off, 64);

                float mn = fmaxf(m, part);
                float sc = __expf(m - mn);
                float pe = __expf(part - mn);
                zs = zs * sc + pe;
                m = mn;
#pragma unroll
                for (int j = 0; j < VEC; j++) acc[j] = acc[j] * sc + pe * xv[j];
            }
        }

        // self-loop (order-invariant under online softmax)
        {
            float rdeg = (end > beg) ? 1.0f / (float)(end - beg) : 1.0f;
            float part = 0.0f;
#pragma unroll
            for (int j = 0; j < VEC; j++) {
                float u = xlv[j] + xrv[j] + wsum[j] * rdeg;
                float h = fmaxf(u, 0.0f) + NEG_SLOPE * fminf(u, 0.0f);
                part += af[j] * h;
            }
#pragma unroll
            for (int off = 32; off; off >>= 1) part += __shfl_xor(part, off, 64);

            float mn = fmaxf(m, part);
            float sc = __expf(m - mn);
            float pe = __expf(part - mn);
            zs = zs * sc + pe;
#pragma unroll
            for (int j = 0; j < VEC; j++) acc[j] = acc[j] * sc + pe * xlv[j];
        }

        float rz = 1.0f / zs;
        if (act) {
            float o[VEC];
#pragma unroll
            for (int j = 0; j < VEC; j++) {
                o[j] = acc[j] * rz + bv[j];
                if (RELU) o[j] = fmaxf(o[j], 0.0f);
            }
            if constexpr (VEC == 4) {
                *(float4*)(out + (size_t)i * C + lane * 4) = make_float4(o[0], o[1], o[2], o[3]);
            } else {
                *(float2*)(out + (size_t)i * C + lane * 2) = make_float2(o[0], o[1]);
            }
        }
    }
}

// ---------- mean pooling per graph (batch_ids sorted); relu folded in ----------
__global__ void k_pool(const float* __restrict__ h, const int* __restrict__ batch,
                       float* __restrict__ pooled) {
    int g = blockIdx.x;
    int lo = 0, hi = NN;
    while (lo < hi) { int mid = (lo + hi) >> 1; if (batch[mid] < g) lo = mid + 1; else hi = mid; }
    int start = lo;
    lo = start; hi = NN;
    while (lo < hi) { int mid = (lo + hi) >> 1; if (batch[mid] < g + 1) lo = mid + 1; else hi = mid; }
    int end = lo;
    float cnt = (float)(end - start);
    int c = threadIdx.x;
    if (c < 200) {
        float acc = 0.0f;
        for (int i = start; i < end; i++) acc += fmaxf(h[(size_t)i * 200 + c], 0.0f);
        pooled[g * 200 + c] = acc / fmaxf(cnt, 1.0f);
    }
}

// ---------- small dense layers on [G, *] ----------
__global__ void k_mlp(const float* __restrict__ X, const float* __restrict__ W,
                      const float* __restrict__ b, float* __restrict__ Y,
                      int Cin, int Cout, int do_relu) {
    int t = blockIdx.x * blockDim.x + threadIdx.x;
    if (t >= GG * Cout) return;
    int g = t / Cout, j = t - g * Cout;
    const float* xrow = X + (size_t)g * Cin;
    float acc = b[j];
    for (int k = 0; k < Cin; k++) acc += xrow[k] * W[k * Cout + j];
    if (do_relu) acc = fmaxf(acc, 0.0f);
    Y[t] = acc;
}

extern "C" void kernel_launch(void* const* d_in, const int* in_sizes, int n_in,
                              void* d_out, int out_size, void* d_ws, size_t ws_size,
                              hipStream_t stream) {
    const float* x   = (const float*)d_in[0];
    const int*   ei  = (const int*)d_in[1];
    const float* ea  = (const float*)d_in[2];
    const int*   bat = (const int*)d_in[3];
    const float* W1l = (const float*)d_in[4];  const float* b1l = (const float*)d_in[5];
    const float* W1r = (const float*)d_in[6];  const float* b1r = (const float*)d_in[7];
    const float* W1e = (const float*)d_in[8];
    const float* a1  = (const float*)d_in[9];  const float* c1  = (const float*)d_in[10];
    const float* W2l = (const float*)d_in[11]; const float* b2l = (const float*)d_in[12];
    const float* W2r = (const float*)d_in[13]; const float* b2r = (const float*)d_in[14];
    const float* W2e = (const float*)d_in[15];
    const float* a2  = (const float*)d_in[16]; const float* c2  = (const float*)d_in[17];
    const float* W3  = (const float*)d_in[18]; const float* b3  = (const float*)d_in[19];
    const float* F1  = (const float*)d_in[20]; const float* bf1 = (const float*)d_in[21];
    const float* F2  = (const float*)d_in[22]; const float* bf2 = (const float*)d_in[23];
    const float* F3  = (const float*)d_in[24]; const float* bf3 = (const float*)d_in[25];

    const int* srcv = ei;        // edge_index[0]
    const int* dstv = ei + EE;   // edge_index[1]

    float* W = (float*)d_ws;
    size_t off = 0;
    int*      hist    = (int*)(W + off); off += NN;
    uint32_t* xlh     = (uint32_t*)(W + off); off += (size_t)NN * 100;   // packed fp16, up to C=200
    float*    xr      = W + off; off += (size_t)NN * 200;
    float*    h1      = W + off; off += (size_t)NN * 100;
    float*    h2      = W + off; off += (size_t)NN * 200;
    int*      rowptr  = (int*)(W + off); off += NN + 4;
    int*      cursor  = (int*)(W + off); off += NN;
    int*      csr_eid = (int*)(W + off); off += EE;
    int*      bsum    = (int*)(W + off); off += 256;
    uint32_t* eah     = (uint32_t*)(W + off); off += (size_t)EE * EAW;
    float*    Wc1     = W + off; off += 16 * 256;
    float*    bc1     = W + off; off += 256;
    float*    Wc2     = W + off; off += 100 * 448;
    float*    bc2     = W + off; off += 448;
    float*    pooled  = W + off; off += (size_t)GG * 200;
    float*    p400    = W + off; off += (size_t)GG * 400;
    float*    y1      = W + off; off += (size_t)GG * 200;
    float*    y2      = W + off; off += (size_t)GG * 100;
    (void)ws_size; (void)n_in; (void)in_sizes; (void)out_size;

    const int B = 256;
    const int NODEB = 12500;   // 4 waves/block -> 50000 waves, 1 node each

    // ---- pack ea to fp16 ----
    k_pack_ea<<<((size_t)EE * EAW + B - 1) / B, B, 0, stream>>>(ea, eah);

    // ---- degree histogram + CSR by dst (real edges only) ----
    (void)hipMemsetAsync(hist, 0, (size_t)NN * sizeof(int), stream);
    k_hist<<<(EE + B - 1) / B, B, 0, stream>>>(dstv, hist);
    k_scan_a<<<NB, 256, 0, stream>>>(hist, bsum);
    k_scan_b<<<1, 1, 0, stream>>>(bsum, rowptr);
    k_scan_c<<<NB, 256, 0, stream>>>(hist, bsum, rowptr);
    k_cursor_init<<<(NN + B - 1) / B, B, 0, stream>>>(rowptr, cursor);
    k_scatter<<<(EE + B - 1) / B, B, 0, stream>>>(dstv, cursor, csr_eid);

    // ---- combined weight matrices ----
    k_combine_w<<<(16 * 256 + B - 1) / B, B, 0, stream>>>(W1l, b1l, W1r, b1r, Wc1, bc1, 16, 100, 256);
    k_combine_w<<<(100 * 448 + B - 1) / B, B, 0, stream>>>(W2l, b2l, W2r, b2r, Wc2, bc2, 100, 200, 448);

    // ---- GAT layer 1: 16 -> 100 ----
    {
        dim3 grid((NN + 63) / 64, 256 / 64);
        k_gemm_dual<16, 256, 100><<<grid, 256, 0, stream>>>(x, Wc1, bc1, xlh, xr);
    }
    k_fused_node<100, 2, 1><<<NODEB, B, 0, stream>>>(rowptr, csr_eid, srcv, eah, W1e, a1, xlh, xr, c1, h1);

    // ---- GAT layer 2: 100 -> 200 ----
    {
        dim3 grid((NN + 63) / 64, 448 / 64);
        k_gemm_dual<100, 448, 200><<<grid, 256, 0, stream>>>(h1, Wc2, bc2, xlh, xr);
    }
    k_fused_node<200, 4, 0><<<NODEB, B, 0, stream>>>(rowptr, csr_eid, srcv, eah, W2e, a2, xlh, xr, c2, h2);

    // ---- pool (mean over graph, relu fused) then W3 + FFN ----
    k_pool<<<GG, 256, 0, stream>>>(h2, bat, pooled);
    k_mlp<<<(GG * 400 + B - 1) / B, B, 0, stream>>>(pooled, W3, b3, p400, 200, 400, 0);
    k_mlp<<<(GG * 200 + B - 1) / B, B, 0, stream>>>(p400, F1, bf1, y1, 400, 200, 1);
    k_mlp<<<(GG * 100 + B - 1) / B, B, 0, stream>>>(y1, F2, bf2, y2, 200, 100, 1);
    k_mlp<<<(GG * 100 + B - 1) / B, B, 0, stream>>>(y2, F3, bf3, (float*)d_out, 100, 100, 0);
}